// Round 16
// baseline (35.028 us; speedup 1.0000x reference)
//
#include <hip/hip_runtime.h>
#include <hip/hip_bf16.h>

#define N_PAIR  4096
#define N_ROW   8192
#define DIM     128
#define NX      8     // col-tiles swept per block
#define NBLOCKS 512   // k_simsum grid (8 x 64)

typedef __attribute__((ext_vector_type(4))) float f32x4;
typedef __attribute__((ext_vector_type(4))) int   i32x4;
typedef __attribute__((ext_vector_type(8))) int   i32x8;

__device__ inline float fast_exp2(float x) {
#if __has_builtin(__builtin_amdgcn_exp2f)
    return __builtin_amdgcn_exp2f(x);
#else
    float r; asm("v_exp_f32 %0, %1" : "=v"(r) : "v"(x)); return r;
#endif
}
__device__ inline float fast_log2(float x) {
#if __has_builtin(__builtin_amdgcn_logf)
    return __builtin_amdgcn_logf(x);
#else
    float r; asm("v_log_f32 %0, %1" : "=v"(r) : "v"(x)); return r;
#endif
}

// K1: interleave + L2-normalize -> zh8 (OCP e4m3 [8192][128]); partner dot -> pd
//     (exact fp32); zero rowsum + done-counter. One pair per wave.
__global__ __launch_bounds__(256) void k_prep(const float* __restrict__ zi,
                                              const float* __restrict__ zj,
                                              unsigned char* __restrict__ zh8,
                                              float* __restrict__ pd,
                                              float* __restrict__ rowsum,
                                              unsigned int* __restrict__ cnt) {
    const int wid  = threadIdx.x >> 6;
    const int lane = threadIdx.x & 63;
    const int k    = blockIdx.x * 4 + wid;
    float2 a = *(const float2*)&zi[k * DIM + lane * 2];
    float2 b = *(const float2*)&zj[k * DIM + lane * 2];
    float ssi = a.x * a.x + a.y * a.y;
    float ssj = b.x * b.x + b.y * b.y;
    float dot = a.x * b.x + a.y * b.y;
#pragma unroll
    for (int off = 1; off < 64; off <<= 1) {
        ssi += __shfl_xor(ssi, off);
        ssj += __shfl_xor(ssj, off);
        dot += __shfl_xor(dot, off);
    }
    const float invi = rsqrtf(ssi), invj = rsqrtf(ssj);
    unsigned int pi = __builtin_amdgcn_cvt_pk_fp8_f32(a.x * invi, a.y * invi, 0, false);
    unsigned int pj = __builtin_amdgcn_cvt_pk_fp8_f32(b.x * invj, b.y * invj, 0, false);
    ((unsigned short*)zh8)[(2 * k)     * (DIM / 2) + lane] = (unsigned short)pi;
    ((unsigned short*)zh8)[(2 * k + 1) * (DIM / 2) + lane] = (unsigned short)pj;
    if (lane == 0) {
        pd[k] = dot * invi * invj;
        rowsum[2 * k]     = 0.f;
        rowsum[2 * k + 1] = 0.f;
        if (k == 0) cnt[0] = 0u;
    }
}

// K2: full-matrix S = Zh*Zh^T via MX-scaled fp8 MFMA (16x16x128, scales = 1.0):
//     8 MFMA + 4 ds_read_b128 per tile per wave, barrier-free hot loop (per-wave
//     private 2x4KB LDS staging, own vmcnt only). Transposed mfma(b,a) -> row
//     lane-local rowsum in registers. End: wc-fold in LDS, 128 global atomics,
//     then the LAST block (device counter; no threadfence — vmcnt-drained
//     device-scope atomics are already coherent) computes the loss inline.
__global__ __launch_bounds__(512, 4) void k_simsum(const unsigned char* __restrict__ zh8,
                                                   float* __restrict__ rowsum,
                                                   const float* __restrict__ pd,
                                                   unsigned int* __restrict__ cnt,
                                                   float* __restrict__ out) {
    __shared__ unsigned char Bs[8 * 8192];          // per-wave: 2 bufs x 4 KB
    __shared__ float rsum_lds[128];
    __shared__ int   s_last;
    __shared__ float wsum[8];
    const int tid  = threadIdx.x;
    const int lane = tid & 63;
    const int wid  = tid >> 6;                      // 0..7
    const int wr   = wid >> 2, wc = wid & 3;        // 64-row strip / 32-col strip
    const int l15  = lane & 15, lhi = lane >> 4;
    const int by   = blockIdx.y;
    const int bx0  = blockIdx.x * NX;
    const int row0 = by * 128 + wr * 64;            // wave's A-row base
    const int wbase = wid * 8192;                   // this wave's LDS region

    if (tid < 128) rsum_lds[tid] = 0.f;
    __syncthreads();                                 // once, before the loop

    // A fragments (whole K=128 per lane-chunk): a[m] = bytes [lhi*32, lhi*32+32)
    i32x8 a[4];
#pragma unroll
    for (int m = 0; m < 4; ++m) {
        const unsigned char* ap = &zh8[(row0 + m * 16 + l15) * DIM + lhi * 32];
        union { i32x4 h[2]; i32x8 v; } u;
        u.h[0] = *(const i32x4*)ap;
        u.h[1] = *(const i32x4*)(ap + 16);
        a[m] = u.v;
    }

    // stage this wave's 32-row B-slice of col-tile ct into its private buf.
    // dest lane-linear; source XOR-swizzled (g = (lane&7)^(rl&7), involution).
    auto stage = [&](int ct, int buf) {
#pragma unroll
        for (int i = 0; i < 4; ++i) {
            const int rl = i * 8 + (lane >> 3);     // 0..31 local row
            const int g  = (lane & 7) ^ (rl & 7);
            const unsigned char* src = zh8 + (ct * 128 + wc * 32 + rl) * DIM + g * 16;
            __builtin_amdgcn_global_load_lds(
                (const __attribute__((address_space(1))) void*)src,
                (__attribute__((address_space(3))) void*)(&Bs[wbase + buf * 4096 + i * 1024]),
                16, 0, 0);
        }
    };

    const float K2E = 2.8853900817779268f;          // 2/ln2: exp(2s)=exp2(K2E*s)
    const int   SC1 = 0x7F7F7F7F;                   // e8m0 scale = 1.0 (all bytes)
    float rs[4] = {0.f, 0.f, 0.f, 0.f};

    stage(bx0, 0);
    asm volatile("s_waitcnt vmcnt(0)" ::: "memory");   // own loads only (per-wave)

    int cur = 0;
#pragma unroll 1
    for (int t = 0; t < NX; ++t) {
        if (t + 1 < NX) stage(bx0 + t + 1, cur ^ 1);   // prefetch into other buf
        const int bx = bx0 + t;
        // b[n]: 32 bytes of local B-row (n*16+l15): chunks c16 = lhi*2, lhi*2+1
        i32x8 b[2];
#pragma unroll
        for (int n = 0; n < 2; ++n) {
            const int rowb = n * 16 + l15;
            const int base = wbase + cur * 4096 + rowb * 128;
            union { i32x4 h[2]; i32x8 v; } u;
            u.h[0] = *(const i32x4*)&Bs[base + (((lhi * 2 + 0) ^ (l15 & 7)) << 4)];
            u.h[1] = *(const i32x4*)&Bs[base + (((lhi * 2 + 1) ^ (l15 & 7)) << 4)];
            b[n] = u.v;
        }
        f32x4 accT[2][4];
        __builtin_amdgcn_s_setprio(1);
#pragma unroll
        for (int n = 0; n < 2; ++n)
#pragma unroll
            for (int m = 0; m < 4; ++m)
                accT[n][m] = __builtin_amdgcn_mfma_scale_f32_16x16x128_f8f6f4(
                    b[n], a[m], (f32x4){0.f, 0.f, 0.f, 0.f},
                    0, 0,              // cbsz/blgp: fp8 e4m3 for both operands
                    0, SC1, 0, SC1);   // opsel/scale A, opsel/scale B (=1.0)
        __builtin_amdgcn_s_setprio(0);
        if (bx == by) {                              // diagonal tile: mask col==row
#pragma unroll
            for (int m = 0; m < 4; ++m) {
                const int rloc = wr * 64 + m * 16 + l15;
                float s0 = 0.f, s1 = 0.f;
#pragma unroll
                for (int n = 0; n < 2; ++n)
#pragma unroll
                    for (int r = 0; r < 4; ++r) {
                        const int cloc = wc * 32 + n * 16 + lhi * 4 + r;
                        float v = fast_exp2(K2E * accT[n][m][r]);
                        v = (cloc == rloc) ? 0.f : v;
                        if (n == 0) s0 += v; else s1 += v;
                    }
                rs[m] += s0 + s1;
            }
        } else {
#pragma unroll
            for (int m = 0; m < 4; ++m) {
                float s0 = 0.f, s1 = 0.f;
#pragma unroll
                for (int n = 0; n < 2; ++n)
#pragma unroll
                    for (int r = 0; r < 4; ++r) {
                        float v = fast_exp2(K2E * accT[n][m][r]);
                        if (n == 0) s0 += v; else s1 += v;
                    }
                rs[m] += s0 + s1;
            }
        }
        if (t + 1 < NX) {
            asm volatile("s_waitcnt vmcnt(0)" ::: "memory");   // own next-buf loads landed
            cur ^= 1;
        }
    }

    // fold lhi groups -> lanes<16 hold per-row partials; wc-fold via LDS, then
    // one global atomic per row per block (128 total).
#pragma unroll
    for (int m = 0; m < 4; ++m) {
        rs[m] += __shfl_xor(rs[m], 16);
        rs[m] += __shfl_xor(rs[m], 32);
    }
    if (lane < 16) {
#pragma unroll
        for (int m = 0; m < 4; ++m)
            atomicAdd(&rsum_lds[wr * 64 + m * 16 + lane], rs[m]);
    }
    __syncthreads();
    if (tid < 128) atomicAdd(&rowsum[by * 128 + tid], rsum_lds[tid]);

    // -------- last block computes the loss (no threadfence: drain own atomics
    // via vmcnt, then bump the device counter; device-scope atomics are
    // coherent at the L2 coherence point once retired) --------
    asm volatile("s_waitcnt vmcnt(0)" ::: "memory");
    __syncthreads();
    if (tid == 0) s_last = (atomicAdd(cnt, 1u) == NBLOCKS - 1) ? 1 : 0;
    __syncthreads();
    if (s_last) {
        const float LN2 = 0.6931471805599453f;
        float local = 0.f;
        for (int i = tid; i < N_ROW; i += 512) {
            float rv = __hip_atomic_load(&rowsum[i], __ATOMIC_RELAXED, __HIP_MEMORY_SCOPE_AGENT);
            local += fast_log2(rv) * LN2 - 2.f * pd[i >> 1];
        }
#pragma unroll
        for (int off = 1; off < 64; off <<= 1) local += __shfl_xor(local, off);
        if (lane == 0) wsum[wid] = local;
        __syncthreads();
        if (tid == 0) {
            float s = 0.f;
#pragma unroll
            for (int w = 0; w < 8; ++w) s += wsum[w];
            out[0] = s * (1.f / (float)N_ROW);
        }
    }
}

extern "C" void kernel_launch(void* const* d_in, const int* in_sizes, int n_in,
                              void* d_out, int out_size, void* d_ws, size_t ws_size,
                              hipStream_t stream) {
    const float* zi = (const float*)d_in[0];
    const float* zj = (const float*)d_in[1];
    char* ws = (char*)d_ws;
    unsigned char* zh8 = (unsigned char*)ws;                           // 1 MiB
    float* rowsum      = (float*)(ws + 2 * 1024 * 1024);               // 32 KiB
    float* pd          = (float*)(ws + 2 * 1024 * 1024 + 32 * 1024);   // 16 KiB
    unsigned int* cnt  = (unsigned int*)(ws + 2 * 1024 * 1024 + 48 * 1024);

    k_prep<<<N_PAIR / 4, 256, 0, stream>>>(zi, zj, zh8, pd, rowsum, cnt);
    dim3 grid(64 / NX, 64);
    k_simsum<<<grid, 512, 0, stream>>>(zh8, rowsum, pd, cnt, (float*)d_out);
}

// Round 17
// 28.600 us; speedup vs baseline: 1.2248x; 1.2248x over previous
//
#include <hip/hip_runtime.h>
#include <hip/hip_bf16.h>

#define N_PAIR 4096
#define N_ROW  8192
#define DIM    128
#define NX     8     // col-tiles swept per block

typedef __attribute__((ext_vector_type(4))) float f32x4;
typedef __attribute__((ext_vector_type(4))) int   i32x4;
typedef __attribute__((ext_vector_type(8))) int   i32x8;

__device__ inline float fast_exp2(float x) {
#if __has_builtin(__builtin_amdgcn_exp2f)
    return __builtin_amdgcn_exp2f(x);
#else
    float r; asm("v_exp_f32 %0, %1" : "=v"(r) : "v"(x)); return r;
#endif
}
__device__ inline float fast_log2(float x) {
#if __has_builtin(__builtin_amdgcn_logf)
    return __builtin_amdgcn_logf(x);
#else
    float r; asm("v_log_f32 %0, %1" : "=v"(r) : "v"(x)); return r;
#endif
}

// K1: interleave + L2-normalize, PRE-SCALED by sqrt(2/ln2) -> zh8 (e4m3):
//     the MFMA then yields K2E*s directly and the epilogue mul disappears.
//     Partner dot -> pd (exact fp32); zero rowsum and out. One pair per wave.
__global__ __launch_bounds__(256) void k_prep(const float* __restrict__ zi,
                                              const float* __restrict__ zj,
                                              unsigned char* __restrict__ zh8,
                                              float* __restrict__ pd,
                                              float* __restrict__ rowsum,
                                              float* __restrict__ out) {
    const int wid  = threadIdx.x >> 6;
    const int lane = threadIdx.x & 63;
    const int k    = blockIdx.x * 4 + wid;
    float2 a = *(const float2*)&zi[k * DIM + lane * 2];
    float2 b = *(const float2*)&zj[k * DIM + lane * 2];
    float ssi = a.x * a.x + a.y * a.y;
    float ssj = b.x * b.x + b.y * b.y;
    float dot = a.x * b.x + a.y * b.y;
#pragma unroll
    for (int off = 1; off < 64; off <<= 1) {
        ssi += __shfl_xor(ssi, off);
        ssj += __shfl_xor(ssj, off);
        dot += __shfl_xor(dot, off);
    }
    const float SCL  = 1.6986436816458534f;   // sqrt(2/ln2)
    const float invi = rsqrtf(ssi), invj = rsqrtf(ssj);
    const float qi = invi * SCL, qj = invj * SCL;
    unsigned int pi = __builtin_amdgcn_cvt_pk_fp8_f32(a.x * qi, a.y * qi, 0, false);
    unsigned int pj = __builtin_amdgcn_cvt_pk_fp8_f32(b.x * qj, b.y * qj, 0, false);
    ((unsigned short*)zh8)[(2 * k)     * (DIM / 2) + lane] = (unsigned short)pi;
    ((unsigned short*)zh8)[(2 * k + 1) * (DIM / 2) + lane] = (unsigned short)pj;
    if (lane == 0) {
        pd[k] = dot * invi * invj;
        rowsum[2 * k]     = 0.f;
        rowsum[2 * k + 1] = 0.f;
        if (k == 0) out[0] = 0.f;
    }
}

// K2: full-matrix S' = Zh*Zh^T (= K2E * cos-sim) via MX-scaled fp8 MFMA
//     (16x16x128, scales = 1.0): 8 MFMA + 4 ds_read_b128 per tile per wave,
//     barrier-free hot loop (per-wave private 2x4KB LDS staging, own vmcnt
//     only). Transposed mfma(b,a) -> row lane-local; epilogue is exp2(acc)+add
//     only. End: wc-fold in LDS, 128 global atomics per block.
__global__ __launch_bounds__(512, 4) void k_simsum(const unsigned char* __restrict__ zh8,
                                                   float* __restrict__ rowsum) {
    __shared__ unsigned char Bs[8 * 8192];          // per-wave: 2 bufs x 4 KB
    __shared__ float rsum_lds[128];
    const int tid  = threadIdx.x;
    const int lane = tid & 63;
    const int wid  = tid >> 6;                      // 0..7
    const int wr   = wid >> 2, wc = wid & 3;        // 64-row strip / 32-col strip
    const int l15  = lane & 15, lhi = lane >> 4;
    const int by   = blockIdx.y;
    const int bx0  = blockIdx.x * NX;
    const int row0 = by * 128 + wr * 64;            // wave's A-row base
    const int wbase = wid * 8192;                   // this wave's LDS region

    if (tid < 128) rsum_lds[tid] = 0.f;
    __syncthreads();                                 // once, before the loop

    // A fragments (whole K=128 per lane-chunk): a[m] = bytes [lhi*32, lhi*32+32)
    i32x8 a[4];
#pragma unroll
    for (int m = 0; m < 4; ++m) {
        const unsigned char* ap = &zh8[(row0 + m * 16 + l15) * DIM + lhi * 32];
        union { i32x4 h[2]; i32x8 v; } u;
        u.h[0] = *(const i32x4*)ap;
        u.h[1] = *(const i32x4*)(ap + 16);
        a[m] = u.v;
    }

    // stage this wave's 32-row B-slice of col-tile ct into its private buf.
    // dest lane-linear; source XOR-swizzled (g = (lane&7)^(rl&7), involution).
    auto stage = [&](int ct, int buf) {
#pragma unroll
        for (int i = 0; i < 4; ++i) {
            const int rl = i * 8 + (lane >> 3);     // 0..31 local row
            const int g  = (lane & 7) ^ (rl & 7);
            const unsigned char* src = zh8 + (ct * 128 + wc * 32 + rl) * DIM + g * 16;
            __builtin_amdgcn_global_load_lds(
                (const __attribute__((address_space(1))) void*)src,
                (__attribute__((address_space(3))) void*)(&Bs[wbase + buf * 4096 + i * 1024]),
                16, 0, 0);
        }
    };

    const int SC1 = 0x7F7F7F7F;                     // e8m0 scale = 1.0 (all bytes)
    float rs[4] = {0.f, 0.f, 0.f, 0.f};

    stage(bx0, 0);
    asm volatile("s_waitcnt vmcnt(0)" ::: "memory");   // own loads only (per-wave)

    int cur = 0;
#pragma unroll 1
    for (int t = 0; t < NX; ++t) {
        if (t + 1 < NX) stage(bx0 + t + 1, cur ^ 1);   // prefetch into other buf
        const int bx = bx0 + t;
        // b[n]: 32 bytes of local B-row (n*16+l15): chunks c16 = lhi*2, lhi*2+1
        i32x8 b[2];
#pragma unroll
        for (int n = 0; n < 2; ++n) {
            const int rowb = n * 16 + l15;
            const int base = wbase + cur * 4096 + rowb * 128;
            union { i32x4 h[2]; i32x8 v; } u;
            u.h[0] = *(const i32x4*)&Bs[base + (((lhi * 2 + 0) ^ (l15 & 7)) << 4)];
            u.h[1] = *(const i32x4*)&Bs[base + (((lhi * 2 + 1) ^ (l15 & 7)) << 4)];
            b[n] = u.v;
        }
        f32x4 accT[2][4];
        __builtin_amdgcn_s_setprio(1);
#pragma unroll
        for (int n = 0; n < 2; ++n)
#pragma unroll
            for (int m = 0; m < 4; ++m)
                accT[n][m] = __builtin_amdgcn_mfma_scale_f32_16x16x128_f8f6f4(
                    b[n], a[m], (f32x4){0.f, 0.f, 0.f, 0.f},
                    0, 0,              // cbsz/blgp: fp8 e4m3 for both operands
                    0, SC1, 0, SC1);   // opsel/scale A, opsel/scale B (=1.0)
        __builtin_amdgcn_s_setprio(0);
        if (bx == by) {                              // diagonal tile: mask col==row
#pragma unroll
            for (int m = 0; m < 4; ++m) {
                const int rloc = wr * 64 + m * 16 + l15;
                float s0 = 0.f, s1 = 0.f;
#pragma unroll
                for (int n = 0; n < 2; ++n)
#pragma unroll
                    for (int r = 0; r < 4; ++r) {
                        const int cloc = wc * 32 + n * 16 + lhi * 4 + r;
                        float v = fast_exp2(accT[n][m][r]);
                        v = (cloc == rloc) ? 0.f : v;
                        if (n == 0) s0 += v; else s1 += v;
                    }
                rs[m] += s0 + s1;
            }
        } else {
#pragma unroll
            for (int m = 0; m < 4; ++m) {
                float s0 = 0.f, s1 = 0.f;
#pragma unroll
                for (int n = 0; n < 2; ++n)
#pragma unroll
                    for (int r = 0; r < 4; ++r) {
                        float v = fast_exp2(accT[n][m][r]);
                        if (n == 0) s0 += v; else s1 += v;
                    }
                rs[m] += s0 + s1;
            }
        }
        if (t + 1 < NX) {
            asm volatile("s_waitcnt vmcnt(0)" ::: "memory");   // own next-buf loads landed
            cur ^= 1;
        }
    }

    // fold lhi groups -> lanes<16 hold per-row partials; wc-fold via LDS, then
    // one global atomic per row per block (128 total).
#pragma unroll
    for (int m = 0; m < 4; ++m) {
        rs[m] += __shfl_xor(rs[m], 16);
        rs[m] += __shfl_xor(rs[m], 32);
    }
    if (lane < 16) {
#pragma unroll
        for (int m = 0; m < 4; ++m)
            atomicAdd(&rsum_lds[wr * 64 + m * 16 + lane], rs[m]);
    }
    __syncthreads();
    if (tid < 128) atomicAdd(&rowsum[by * 128 + tid], rsum_lds[tid]);
}

// K3: 32 blocks x 256 thr; per-block pre-divided float atomic into out
//     (out zeroed by k_prep, stream-ordered; replay-deterministic).
__global__ __launch_bounds__(256) void k_loss(const float* __restrict__ rowsum,
                                              const float* __restrict__ pd,
                                              float* __restrict__ out) {
    const int tid  = threadIdx.x;
    const int lane = tid & 63;
    const int wid  = tid >> 6;
    const int i    = blockIdx.x * 256 + tid;        // 0..8191
    const float LN2 = 0.6931471805599453f;
    float local = fast_log2(rowsum[i]) * LN2 - 2.f * pd[i >> 1];
#pragma unroll
    for (int off = 1; off < 64; off <<= 1) local += __shfl_xor(local, off);
    __shared__ float wsum[4];
    if (lane == 0) wsum[wid] = local;
    __syncthreads();
    if (tid == 0)
        atomicAdd(out, (wsum[0] + wsum[1] + wsum[2] + wsum[3]) * (1.f / (float)N_ROW));
}

extern "C" void kernel_launch(void* const* d_in, const int* in_sizes, int n_in,
                              void* d_out, int out_size, void* d_ws, size_t ws_size,
                              hipStream_t stream) {
    const float* zi = (const float*)d_in[0];
    const float* zj = (const float*)d_in[1];
    char* ws = (char*)d_ws;
    unsigned char* zh8 = (unsigned char*)ws;                      // 1 MiB
    float* rowsum = (float*)(ws + 2 * 1024 * 1024);               // 32 KiB
    float* pd     = (float*)(ws + 2 * 1024 * 1024 + 32 * 1024);   // 16 KiB

    k_prep<<<N_PAIR / 4, 256, 0, stream>>>(zi, zj, zh8, pd, rowsum, (float*)d_out);
    dim3 grid(64 / NX, 64);
    k_simsum<<<grid, 512, 0, stream>>>(zh8, rowsum);
    k_loss<<<N_ROW / 256, 256, 0, stream>>>(rowsum, pd, (float*)d_out);
}